// Round 2
// baseline (8818.210 us; speedup 1.0000x reference)
//
#include <hip/hip_runtime.h>

using short8 = __attribute__((ext_vector_type(8))) short;
using f32x4  = __attribute__((ext_vector_type(4))) float;

#define NT     512
#define NBATCH 64
#define NN     1024
#define NIN    24
#define OBS_ELEMS (NBATCH * NN)   // one ping-pong buffer, bf16 elems

__device__ __forceinline__ unsigned short f2bf(float x) {
  union { float f; unsigned u; } v; v.f = x;
  return (unsigned short)((v.u + 0x7FFFu + ((v.u >> 16) & 1u)) >> 16);
}

// 256 WGs x 64 threads (1 wave each). WG (bg, ig): batches [16*bg,16*bg+16),
// neurons [16*ig, 16*ig+16). Full K=1024 recurrent GEMM per wave via MFMA,
// W fragments persistent in VGPRs. Hand-rolled 64-WG barrier per bg group.
// Plain launch: 256 waves << 8192-wave device capacity -> all blocks resident
// under any packing; no cooperative launch needed.
__global__ __launch_bounds__(64, 1) void rnn_step_all(
    const float* __restrict__ u,    // (64, 512, 24)
    const float* __restrict__ r0,   // (1, 64, 1024)
    const float* __restrict__ W,    // (1024, 1024)
    const float* __restrict__ Bm,   // (1024, 24)
    const float* __restrict__ tau,  // (1024,)
    const float* __restrict__ ds,   // (1024,) dales sign
    float* __restrict__ out,        // r_output (64,512,1024) then r_final (64,1024)
    unsigned int* __restrict__ cnt, // 4 counters, 64B apart
    unsigned short* __restrict__ obs) // 2 x (64,1024) bf16 ping-pong
{
  const int lane = threadIdx.x;
  const int bid  = blockIdx.x;
  // XCD-pair swizzle: bg group g occupies XCD classes {2g, 2g+1} (round-robin
  // assumption; correctness does not depend on it).
  const int c  = bid & 7;
  const int bg = c >> 1;                       // 0..3
  const int ig = ((bid >> 3) << 1) | (c & 1);  // 0..63
  const int b0 = bg * 16, i0 = ig * 16;
  const int lr = lane & 15, lg = lane >> 4;
  const int i  = i0 + lr;                      // this lane's neuron (B/D col)

  // ---- persistent W fragments (MFMA B operand): B[k][col] = W[i0+col][kb*32+k]*sign ----
  short8 wf[32];
#pragma unroll
  for (int kb = 0; kb < 32; ++kb) {
    const int j0 = kb * 32 + lg * 8;
    const float* wp = W + (size_t)i * NN + j0;
    f32x4 w0 = *(const f32x4*)(wp);
    f32x4 w1 = *(const f32x4*)(wp + 4);
    f32x4 s0 = *(const f32x4*)(ds + j0);
    f32x4 s1 = *(const f32x4*)(ds + j0 + 4);
    short8 f;
    f[0] = (short)f2bf(w0[0] * s0[0]);
    f[1] = (short)f2bf(w0[1] * s0[1]);
    f[2] = (short)f2bf(w0[2] * s0[2]);
    f[3] = (short)f2bf(w0[3] * s0[3]);
    f[4] = (short)f2bf(w1[0] * s1[0]);
    f[5] = (short)f2bf(w1[1] * s1[1]);
    f[6] = (short)f2bf(w1[2] * s1[2]);
    f[7] = (short)f2bf(w1[3] * s1[3]);
    wf[kb] = f;
  }

  // ---- input-matrix fragment: B[k=m][col] = Bm[i0+col][m], m<24 else 0 ----
  short8 bin;
#pragma unroll
  for (int e = 0; e < 8; ++e) {
    const int m = lg * 8 + e;
    bin[e] = (short)f2bf(m < NIN ? Bm[(size_t)i * NIN + m] : 0.0f);
  }

  const float itau = 1.0f / tau[i];

  // ---- init r (C/D layout: row=lg*4+q -> batch, col=lr -> neuron), write obs buf0 ----
  f32x4 r;
#pragma unroll
  for (int q = 0; q < 4; ++q) {
    const int b = b0 + lg * 4 + q;
    r[q] = r0[(size_t)b * NN + i];
    obs[(size_t)b * NN + i] = f2bf(r[q] > 0.0f ? r[q] : 0.0f);
  }

  // ---- barrier among the 64 WGs of this bg group ----
  unsigned int* mycnt = cnt + bg * 16;  // 64B apart
  unsigned int sync_no = 0;
  auto barrier = [&]() {
    __threadfence();  // release: L2 writeback so peers (other XCD) see obs stores
    if (lane == 0)
      __hip_atomic_fetch_add(mycnt, 1u, __ATOMIC_RELAXED, __HIP_MEMORY_SCOPE_AGENT);
    ++sync_no;
    const unsigned int tgt = 64u * sync_no;
    while (__hip_atomic_load(mycnt, __ATOMIC_RELAXED, __HIP_MEMORY_SCOPE_AGENT) < tgt)
      __builtin_amdgcn_s_sleep(2);
    __threadfence();  // acquire: invalidate stale cached lines before reading peers' obs
  };

  const float* up_base = u + (size_t)(b0 + lr) * NT * NIN;  // A-row batch = b0+lr

  // prefetch u for t=0 (completes while spinning in the initial barrier)
  f32x4 up0 = {0.f, 0.f, 0.f, 0.f}, up1 = {0.f, 0.f, 0.f, 0.f};
  if (lg < 3) {
    up0 = *(const f32x4*)(up_base + lg * 8);
    up1 = *(const f32x4*)(up_base + lg * 8 + 4);
  }

  barrier();  // initial obs visible to the group

  for (int t = 0; t < NT; ++t) {
    const unsigned short* ob = obs + ((t & 1) ? OBS_ELEMS : 0);
    unsigned short*       ow = obs + ((t & 1) ? 0 : OBS_ELEMS);

    f32x4 acc  = {0.f, 0.f, 0.f, 0.f};
    f32x4 acc1 = {0.f, 0.f, 0.f, 0.f};

    // input k-block: A[row=lr][k=m] = u[b0+lr][t][m] (bf16), m>=24 zero-padded
    short8 ua = {0, 0, 0, 0, 0, 0, 0, 0};
    ua[0] = (short)f2bf(up0[0]);
    ua[1] = (short)f2bf(up0[1]);
    ua[2] = (short)f2bf(up0[2]);
    ua[3] = (short)f2bf(up0[3]);
    ua[4] = (short)f2bf(up1[0]);
    ua[5] = (short)f2bf(up1[1]);
    ua[6] = (short)f2bf(up1[2]);
    ua[7] = (short)f2bf(up1[3]);
    if (lg >= 3) ua = short8{0, 0, 0, 0, 0, 0, 0, 0};
    acc = __builtin_amdgcn_mfma_f32_16x16x32_bf16(ua, bin, acc, 0, 0, 0);

    // recurrent GEMM: A[row=lr][k] = obs[b0+lr][kb*32 + lg*8 + e]
    const unsigned short* orow = ob + (size_t)(b0 + lr) * NN + lg * 8;
#pragma unroll
    for (int kb = 0; kb < 32; kb += 2) {
      short8 a0 = *(const short8*)(orow + kb * 32);
      short8 a1 = *(const short8*)(orow + kb * 32 + 32);
      acc  = __builtin_amdgcn_mfma_f32_16x16x32_bf16(a0, wf[kb],     acc,  0, 0, 0);
      acc1 = __builtin_amdgcn_mfma_f32_16x16x32_bf16(a1, wf[kb + 1], acc1, 0, 0, 0);
    }

    // prefetch u for t+1 (latency hides under the end-of-step barrier spin)
    if (t != NT - 1 && lg < 3) {
      const float* up = up_base + (t + 1) * NIN + lg * 8;
      up0 = *(const f32x4*)(up);
      up1 = *(const f32x4*)(up + 4);
    }

    // update + stores (this wave owns its (b,i) tile's state)
#pragma unroll
    for (int q = 0; q < 4; ++q) {
      const int b = b0 + lg * 4 + q;
      const float pre = acc[q] + acc1[q];
      // act = 30*(1+tanh(0.14*pre-4.2)) = 60*sigmoid(0.28*pre-8.4)
      const float act = 60.0f / (1.0f + expf(8.4f - 0.28f * pre));
      const float rv  = r[q] + (0.1f * (act - r[q])) * itau;
      r[q] = rv;
      __builtin_nontemporal_store(rv, &out[((size_t)b * NT + t) * NN + i]);
      ow[(size_t)b * NN + i] = f2bf(rv > 0.0f ? rv : 0.0f);
    }

    if (t != NT - 1) barrier();
  }

  // r_final
#pragma unroll
  for (int q = 0; q < 4; ++q) {
    const int b = b0 + lg * 4 + q;
    out[(size_t)NBATCH * NT * NN + (size_t)b * NN + i] = r[q];
  }
}

extern "C" void kernel_launch(void* const* d_in, const int* in_sizes, int n_in,
                              void* d_out, int out_size, void* d_ws, size_t ws_size,
                              hipStream_t stream) {
  const float* u   = (const float*)d_in[0];
  const float* r0  = (const float*)d_in[1];
  const float* W   = (const float*)d_in[2];
  const float* Bm  = (const float*)d_in[3];
  const float* tau = (const float*)d_in[4];
  const float* ds  = (const float*)d_in[5];
  float* out = (float*)d_out;

  unsigned int*   cnt = (unsigned int*)d_ws;
  unsigned short* obs = (unsigned short*)((char*)d_ws + 256);

  // zero the 4 barrier counters (part of every call, incl. graph replays -> deterministic)
  hipMemsetAsync(d_ws, 0, 256, stream);

  rnn_step_all<<<dim3(256), dim3(64), 0, stream>>>(u, r0, W, Bm, tau, ds, out, cnt, obs);
}

// Round 3
// 4461.488 us; speedup vs baseline: 1.9765x; 1.9765x over previous
//
#include <hip/hip_runtime.h>

using short8 = __attribute__((ext_vector_type(8))) short;
using f32x4  = __attribute__((ext_vector_type(4))) float;

#define NT     512
#define NBATCH 64
#define NN     1024
#define NIN    24
#define OBS_ELEMS (NBATCH * NN)   // one ping-pong buffer, bf16 elems
#define SCOPE_AGENT __HIP_MEMORY_SCOPE_AGENT

__device__ __forceinline__ unsigned short f2bf(float x) {
  union { float f; unsigned u; } v; v.f = x;
  return (unsigned short)((v.u + 0x7FFFu + ((v.u >> 16) & 1u)) >> 16);
}

// 256 WGs x 64 threads (1 wave each). WG (bg, ig): batches [16*bg,16*bg+16),
// neurons [16*ig, 16*ig+16). Full K=1024 recurrent GEMM per wave via MFMA,
// W fragments persistent in VGPRs.
//
// Sync redesign (R2): flag-array barrier at L3.
//  - obs stores are relaxed agent-scope (sc1 write-through -> Infinity Cache),
//    so the release side is only s_waitcnt vmcnt(0) + one flag store (no wbl2).
//  - each WG stores flags[bg*64+ig]=sync_no; each lane polls flags[bg*64+lane];
//    barrier passes when __all(flag >= sync_no). No RMW atomics at all.
//  - one agent acquire fence (buffer_inv) after the poll invalidates stale
//    clean L2 lines of the ping-pong obs buffers.
//  - out stores + u prefetch issued AFTER the flag store -> overlap the spin.
__global__ __launch_bounds__(64, 1) void rnn_step_all(
    const float* __restrict__ u,    // (64, 512, 24)
    const float* __restrict__ r0,   // (1, 64, 1024)
    const float* __restrict__ W,    // (1024, 1024)
    const float* __restrict__ Bm,   // (1024, 24)
    const float* __restrict__ tau,  // (1024,)
    const float* __restrict__ ds,   // (1024,) dales sign
    float* __restrict__ out,        // r_output (64,512,1024) then r_final (64,1024)
    unsigned int* __restrict__ flags, // 4 groups x 64 flags
    unsigned short* __restrict__ obs) // 2 x (64,1024) bf16 ping-pong
{
  const int lane = threadIdx.x;
  const int bid  = blockIdx.x;
  const int c  = bid & 7;
  const int bg = c >> 1;                       // 0..3 batch group
  const int ig = ((bid >> 3) << 1) | (c & 1);  // 0..63 neuron group
  const int b0 = bg * 16, i0 = ig * 16;
  const int lr = lane & 15, lg = lane >> 4;
  const int i  = i0 + lr;                      // this lane's neuron (B/D col)

  unsigned int* gflags = flags + bg * 64;

  // ---- persistent W fragments (MFMA B operand): B[k][col] = W[i0+col][kb*32+k]*sign ----
  short8 wf[32];
#pragma unroll
  for (int kb = 0; kb < 32; ++kb) {
    const int j0 = kb * 32 + lg * 8;
    const float* wp = W + (size_t)i * NN + j0;
    f32x4 w0 = *(const f32x4*)(wp);
    f32x4 w1 = *(const f32x4*)(wp + 4);
    f32x4 s0 = *(const f32x4*)(ds + j0);
    f32x4 s1 = *(const f32x4*)(ds + j0 + 4);
    short8 f;
    f[0] = (short)f2bf(w0[0] * s0[0]);
    f[1] = (short)f2bf(w0[1] * s0[1]);
    f[2] = (short)f2bf(w0[2] * s0[2]);
    f[3] = (short)f2bf(w0[3] * s0[3]);
    f[4] = (short)f2bf(w1[0] * s1[0]);
    f[5] = (short)f2bf(w1[1] * s1[1]);
    f[6] = (short)f2bf(w1[2] * s1[2]);
    f[7] = (short)f2bf(w1[3] * s1[3]);
    wf[kb] = f;
  }

  // ---- input-matrix fragment: B[k=m][col] = Bm[i0+col][m], m<24 else 0 ----
  short8 bin;
#pragma unroll
  for (int e = 0; e < 8; ++e) {
    const int m = lg * 8 + e;
    bin[e] = (short)f2bf(m < NIN ? Bm[(size_t)i * NIN + m] : 0.0f);
  }

  const float itau = 1.0f / tau[i];

  // ---- init r (C/D layout: row(batch)=lg*4+q, col(neuron)=lr), write obs buf0 ----
  f32x4 r;
#pragma unroll
  for (int q = 0; q < 4; ++q) {
    const int b = b0 + lg * 4 + q;
    r[q] = r0[(size_t)b * NN + i];
    __hip_atomic_store(&obs[(size_t)b * NN + i], f2bf(r[q] > 0.0f ? r[q] : 0.0f),
                       __ATOMIC_RELAXED, SCOPE_AGENT);
  }

  // signal arrival #1
  asm volatile("s_waitcnt vmcnt(0)" ::: "memory");
  if (lane == 0)
    __hip_atomic_store(&gflags[ig], 1u, __ATOMIC_RELAXED, SCOPE_AGENT);

  const float* up_base = u + (size_t)(b0 + lr) * NT * NIN;  // A-row batch = b0+lr

  // prefetch u for t=0 (completes while spinning)
  f32x4 up0 = {0.f, 0.f, 0.f, 0.f}, up1 = {0.f, 0.f, 0.f, 0.f};
  if (lg < 3) {
    up0 = *(const f32x4*)(up_base + lg * 8);
    up1 = *(const f32x4*)(up_base + lg * 8 + 4);
  }

  // wait #1
  {
    unsigned int x;
    do {
      x = __hip_atomic_load(&gflags[lane], __ATOMIC_RELAXED, SCOPE_AGENT);
    } while (!__all((int)(x >= 1u)));
    __builtin_amdgcn_fence(__ATOMIC_ACQUIRE, "agent");
  }

  for (int t = 0; t < NT; ++t) {
    const unsigned short* ob = obs + ((t & 1) ? OBS_ELEMS : 0);
    unsigned short*       ow = obs + ((t & 1) ? 0 : OBS_ELEMS);

    f32x4 acc  = {0.f, 0.f, 0.f, 0.f};
    f32x4 acc1 = {0.f, 0.f, 0.f, 0.f};

    // input k-block: A[row=lr][k=m] = u[b0+lr][t][m] (bf16), m>=24 zero-padded
    short8 ua;
    ua[0] = (short)f2bf(up0[0]);
    ua[1] = (short)f2bf(up0[1]);
    ua[2] = (short)f2bf(up0[2]);
    ua[3] = (short)f2bf(up0[3]);
    ua[4] = (short)f2bf(up1[0]);
    ua[5] = (short)f2bf(up1[1]);
    ua[6] = (short)f2bf(up1[2]);
    ua[7] = (short)f2bf(up1[3]);
    if (lg >= 3) ua = short8{0, 0, 0, 0, 0, 0, 0, 0};
    acc = __builtin_amdgcn_mfma_f32_16x16x32_bf16(ua, bin, acc, 0, 0, 0);

    // recurrent GEMM: A[row=lr][k] = obs[b0+lr][kb*32 + lg*8 + e]
    const unsigned short* orow = ob + (size_t)(b0 + lr) * NN + lg * 8;
#pragma unroll
    for (int kb = 0; kb < 32; kb += 2) {
      short8 a0 = *(const short8*)(orow + kb * 32);
      short8 a1 = *(const short8*)(orow + kb * 32 + 32);
      acc  = __builtin_amdgcn_mfma_f32_16x16x32_bf16(a0, wf[kb],     acc,  0, 0, 0);
      acc1 = __builtin_amdgcn_mfma_f32_16x16x32_bf16(a1, wf[kb + 1], acc1, 0, 0, 0);
    }

    // state update
    f32x4 rv;
#pragma unroll
    for (int q = 0; q < 4; ++q) {
      const float pre = acc[q] + acc1[q];
      // act = 30*(1+tanh(0.14*pre-4.2)) = 60*sigmoid(0.28*pre-8.4)
      const float act = 60.0f / (1.0f + expf(8.4f - 0.28f * pre));
      rv[q] = r[q] + (0.1f * (act - r[q])) * itau;
      r[q]  = rv[q];
    }

    if (t != NT - 1) {
      // publish obs (write-through to L3), then release: vmcnt(0) + flag store
#pragma unroll
      for (int q = 0; q < 4; ++q) {
        const int b = b0 + lg * 4 + q;
        __hip_atomic_store(&ow[(size_t)b * NN + i],
                           f2bf(rv[q] > 0.0f ? rv[q] : 0.0f),
                           __ATOMIC_RELAXED, SCOPE_AGENT);
      }
      asm volatile("s_waitcnt vmcnt(0)" ::: "memory");
      if (lane == 0)
        __hip_atomic_store(&gflags[ig], (unsigned int)(t + 2),
                           __ATOMIC_RELAXED, SCOPE_AGENT);
    }

    // off-critical-path work overlaps the spin below
#pragma unroll
    for (int q = 0; q < 4; ++q) {
      const int b = b0 + lg * 4 + q;
      __builtin_nontemporal_store(rv[q], &out[((size_t)b * NT + t) * NN + i]);
    }
    if (t != NT - 1) {
      if (lg < 3) {
        const float* up = up_base + (t + 1) * NIN + lg * 8;
        up0 = *(const f32x4*)(up);
        up1 = *(const f32x4*)(up + 4);
      }
      const unsigned int tgt = (unsigned int)(t + 2);
      unsigned int x;
      do {
        x = __hip_atomic_load(&gflags[lane], __ATOMIC_RELAXED, SCOPE_AGENT);
      } while (!__all((int)(x >= tgt)));
      __builtin_amdgcn_fence(__ATOMIC_ACQUIRE, "agent");
    }
  }

  // r_final
#pragma unroll
  for (int q = 0; q < 4; ++q) {
    const int b = b0 + lg * 4 + q;
    out[(size_t)NBATCH * NT * NN + (size_t)b * NN + i] = r[q];
  }
}

extern "C" void kernel_launch(void* const* d_in, const int* in_sizes, int n_in,
                              void* d_out, int out_size, void* d_ws, size_t ws_size,
                              hipStream_t stream) {
  const float* u   = (const float*)d_in[0];
  const float* r0  = (const float*)d_in[1];
  const float* W   = (const float*)d_in[2];
  const float* Bm  = (const float*)d_in[3];
  const float* tau = (const float*)d_in[4];
  const float* ds  = (const float*)d_in[5];
  float* out = (float*)d_out;

  unsigned int*   flags = (unsigned int*)d_ws;
  unsigned short* obs   = (unsigned short*)((char*)d_ws + 4096);

  // zero the flag region every call (incl. graph replays -> deterministic)
  hipMemsetAsync(d_ws, 0, 4096, stream);

  rnn_step_all<<<dim3(256), dim3(64), 0, stream>>>(u, r0, W, Bm, tau, ds, out, flags, obs);
}

// Round 4
// 4188.203 us; speedup vs baseline: 2.1055x; 1.0653x over previous
//
#include <hip/hip_runtime.h>

using short8 = __attribute__((ext_vector_type(8))) short;
using f32x4  = __attribute__((ext_vector_type(4))) float;

#define NT     512
#define NBATCH 64
#define NN     1024
#define NIN    24
#define OBS_ELEMS (NBATCH * NN)   // one ping-pong buffer, bf16 elems
#define SCOPE_AGENT __HIP_MEMORY_SCOPE_AGENT

__device__ __forceinline__ unsigned short f2bf(float x) {
  union { float f; unsigned u; } v; v.f = x;
  return (unsigned short)((v.u + 0x7FFFu + ((v.u >> 16) & 1u)) >> 16);
}

// R3: 64 WGs x 256 threads (4 waves). WG (bg, ig4): batches [16*bg, +16),
// neurons [64*ig4, +64); wave w owns neurons [64*ig4+16*w, +16).
// Sync group = 16 WGs (one batch group). Flags: 16 x u16 = one cacheline per
// group; only wave 0 polls (s_sleep backoff), __syncthreads releases the WG.
// Release: obs sc1 stores -> per-wave vmcnt(0) -> s_barrier -> 1 flag store.
// W fragments persistent in VGPRs; full K=1024 per wave via 33 MFMA/step.
__global__ __launch_bounds__(256, 1) void rnn_step_all(
    const float* __restrict__ u,    // (64, 512, 24)
    const float* __restrict__ r0,   // (1, 64, 1024)
    const float* __restrict__ W,    // (1024, 1024)
    const float* __restrict__ Bm,   // (1024, 24)
    const float* __restrict__ tau,  // (1024,)
    const float* __restrict__ ds,   // (1024,) dales sign
    float* __restrict__ out,        // r_output (64,512,1024) then r_final (64,1024)
    unsigned short* __restrict__ flags, // 4 groups x 32 u16 (64B apart)
    unsigned short* __restrict__ obs)   // 2 x (64,1024) bf16 ping-pong
{
  const int tid  = threadIdx.x;
  const int wave = tid >> 6;
  const int lane = tid & 63;
  const int bid  = blockIdx.x;
  const int bg   = bid & 3;        // batch group; XCD classes {bg, bg+4} under round-robin
  const int ig4  = bid >> 2;       // 0..15 neuron super-group
  const int b0 = bg * 16;
  const int lr = lane & 15, lg = lane >> 4;
  const int i  = ig4 * 64 + wave * 16 + lr;   // this lane's neuron (B/D col)

  unsigned short* gflags = flags + bg * 32;   // one 64B line per group

  // ---- persistent W fragments (MFMA B operand): B[k][col] = W[i0+col][kb*32+k]*sign ----
  short8 wf[32];
#pragma unroll
  for (int kb = 0; kb < 32; ++kb) {
    const int j0 = kb * 32 + lg * 8;
    const float* wp = W + (size_t)i * NN + j0;
    f32x4 w0 = *(const f32x4*)(wp);
    f32x4 w1 = *(const f32x4*)(wp + 4);
    f32x4 s0 = *(const f32x4*)(ds + j0);
    f32x4 s1 = *(const f32x4*)(ds + j0 + 4);
    short8 f;
    f[0] = (short)f2bf(w0[0] * s0[0]);
    f[1] = (short)f2bf(w0[1] * s0[1]);
    f[2] = (short)f2bf(w0[2] * s0[2]);
    f[3] = (short)f2bf(w0[3] * s0[3]);
    f[4] = (short)f2bf(w1[0] * s1[0]);
    f[5] = (short)f2bf(w1[1] * s1[1]);
    f[6] = (short)f2bf(w1[2] * s1[2]);
    f[7] = (short)f2bf(w1[3] * s1[3]);
    wf[kb] = f;
  }

  // ---- input-matrix fragment: B[k=m][col] = Bm[i0+col][m], m<24 else 0 ----
  short8 bin;
#pragma unroll
  for (int e = 0; e < 8; ++e) {
    const int m = lg * 8 + e;
    bin[e] = (short)f2bf(m < NIN ? Bm[(size_t)i * NIN + m] : 0.0f);
  }

  const float itau = 1.0f / tau[i];

  // ---- init r (C/D layout: row(batch)=lg*4+q, col(neuron)=lr), publish obs buf0 ----
  f32x4 r;
#pragma unroll
  for (int q = 0; q < 4; ++q) {
    const int b = b0 + lg * 4 + q;
    r[q] = r0[(size_t)b * NN + i];
    __hip_atomic_store(&obs[(size_t)b * NN + i], f2bf(r[q] > 0.0f ? r[q] : 0.0f),
                       __ATOMIC_RELAXED, SCOPE_AGENT);
  }

  // arrival #1
  asm volatile("s_waitcnt vmcnt(0)" ::: "memory");
  __syncthreads();
  if (tid == 0)
    __hip_atomic_store(&gflags[ig4], (unsigned short)1, __ATOMIC_RELAXED, SCOPE_AGENT);

  const float* up_base = u + (size_t)(b0 + lr) * NT * NIN;  // A-row batch = b0+lr

  // prefetch u for t=0 (completes while waiting)
  f32x4 up0 = {0.f, 0.f, 0.f, 0.f}, up1 = {0.f, 0.f, 0.f, 0.f};
  if (lg < 3) {
    up0 = *(const f32x4*)(up_base + lg * 8);
    up1 = *(const f32x4*)(up_base + lg * 8 + 4);
  }

  // wait #1: wave 0 polls the group's flag line, then releases the WG
  if (wave == 0) {
    for (;;) {
      unsigned short x =
          __hip_atomic_load(&gflags[lane & 15], __ATOMIC_RELAXED, SCOPE_AGENT);
      if (__all((int)(x >= 1))) break;
      __builtin_amdgcn_s_sleep(1);
    }
  }
  __syncthreads();
  __builtin_amdgcn_fence(__ATOMIC_ACQUIRE, "agent");

  for (int t = 0; t < NT; ++t) {
    const unsigned short* ob = obs + ((t & 1) ? OBS_ELEMS : 0);
    unsigned short*       ow = obs + ((t & 1) ? 0 : OBS_ELEMS);

    f32x4 acc  = {0.f, 0.f, 0.f, 0.f};
    f32x4 acc1 = {0.f, 0.f, 0.f, 0.f};

    // input k-block: A[row=lr][k=m] = u[b0+lr][t][m] (bf16), m>=24 zero-padded
    short8 ua;
    ua[0] = (short)f2bf(up0[0]);
    ua[1] = (short)f2bf(up0[1]);
    ua[2] = (short)f2bf(up0[2]);
    ua[3] = (short)f2bf(up0[3]);
    ua[4] = (short)f2bf(up1[0]);
    ua[5] = (short)f2bf(up1[1]);
    ua[6] = (short)f2bf(up1[2]);
    ua[7] = (short)f2bf(up1[3]);
    if (lg >= 3) ua = short8{0, 0, 0, 0, 0, 0, 0, 0};
    acc = __builtin_amdgcn_mfma_f32_16x16x32_bf16(ua, bin, acc, 0, 0, 0);

    // recurrent GEMM: A[row=lr][k] = obs[b0+lr][kb*32 + lg*8 + e]
    const unsigned short* orow = ob + (size_t)(b0 + lr) * NN + lg * 8;
#pragma unroll
    for (int kb = 0; kb < 32; kb += 2) {
      short8 a0 = *(const short8*)(orow + kb * 32);
      short8 a1 = *(const short8*)(orow + kb * 32 + 32);
      acc  = __builtin_amdgcn_mfma_f32_16x16x32_bf16(a0, wf[kb],     acc,  0, 0, 0);
      acc1 = __builtin_amdgcn_mfma_f32_16x16x32_bf16(a1, wf[kb + 1], acc1, 0, 0, 0);
    }

    // state update
    f32x4 rv;
#pragma unroll
    for (int q = 0; q < 4; ++q) {
      const float pre = acc[q] + acc1[q];
      // act = 30*(1+tanh(0.14*pre-4.2)) = 60*sigmoid(0.28*pre-8.4)
      const float act = 60.0f / (1.0f + expf(8.4f - 0.28f * pre));
      rv[q] = r[q] + (0.1f * (act - r[q])) * itau;
      r[q]  = rv[q];
    }

    if (t != NT - 1) {
      // publish obs, release: per-wave vmcnt(0), WG barrier, one flag store
#pragma unroll
      for (int q = 0; q < 4; ++q) {
        const int b = b0 + lg * 4 + q;
        __hip_atomic_store(&ow[(size_t)b * NN + i],
                           f2bf(rv[q] > 0.0f ? rv[q] : 0.0f),
                           __ATOMIC_RELAXED, SCOPE_AGENT);
      }
      asm volatile("s_waitcnt vmcnt(0)" ::: "memory");
      __syncthreads();
      if (tid == 0)
        __hip_atomic_store(&gflags[ig4], (unsigned short)(t + 2),
                           __ATOMIC_RELAXED, SCOPE_AGENT);
    }

    // off-critical-path: out stores + u prefetch overlap the wait
#pragma unroll
    for (int q = 0; q < 4; ++q) {
      const int b = b0 + lg * 4 + q;
      __builtin_nontemporal_store(rv[q], &out[((size_t)b * NT + t) * NN + i]);
    }
    if (t != NT - 1) {
      if (lg < 3) {
        const float* up = up_base + (t + 1) * NIN + lg * 8;
        up0 = *(const f32x4*)(up);
        up1 = *(const f32x4*)(up + 4);
      }
      const unsigned short tgt = (unsigned short)(t + 2);
      if (wave == 0) {
        for (;;) {
          unsigned short x =
              __hip_atomic_load(&gflags[lane & 15], __ATOMIC_RELAXED, SCOPE_AGENT);
          if (__all((int)(x >= tgt))) break;
          __builtin_amdgcn_s_sleep(1);
        }
      }
      __syncthreads();
      __builtin_amdgcn_fence(__ATOMIC_ACQUIRE, "agent");
    }
  }

  // r_final
#pragma unroll
  for (int q = 0; q < 4; ++q) {
    const int b = b0 + lg * 4 + q;
    out[(size_t)NBATCH * NT * NN + (size_t)b * NN + i] = r[q];
  }
}

extern "C" void kernel_launch(void* const* d_in, const int* in_sizes, int n_in,
                              void* d_out, int out_size, void* d_ws, size_t ws_size,
                              hipStream_t stream) {
  const float* u   = (const float*)d_in[0];
  const float* r0  = (const float*)d_in[1];
  const float* W   = (const float*)d_in[2];
  const float* Bm  = (const float*)d_in[3];
  const float* tau = (const float*)d_in[4];
  const float* ds  = (const float*)d_in[5];
  float* out = (float*)d_out;

  unsigned short* flags = (unsigned short*)d_ws;
  unsigned short* obs   = (unsigned short*)((char*)d_ws + 4096);

  // zero the flag region every call (incl. graph replays -> deterministic)
  hipMemsetAsync(d_ws, 0, 4096, stream);

  rnn_step_all<<<dim3(64), dim3(256), 0, stream>>>(u, r0, W, Bm, tau, ds, out, flags, obs);
}